// Round 3
// baseline (306.320 us; speedup 1.0000x reference)
//
#include <hip/hip_runtime.h>
#include <stdint.h>
#include <math.h>

#define NPTS 262144
#define NB 4
#define KSEL 4096
#define CAP 6144

// ---- workspace layout (bytes) ----
#define OFF_BITS  0ULL
#define OFF_H1    (4ULL*NPTS*NB)                  // 4,194,304
#define OFF_H2    (OFF_H1 + 4ULL*65536*NB)        // +1 MB
#define OFF_CTRL  (OFF_H2 + 4ULL*65536*NB)        // +1 MB
#define OFF_CAND  (OFF_CTRL + 1024ULL)
#define OFF_WF    (OFF_CAND + 8ULL*CAP*NB)
#define WS_NEEDED (OFF_WF + 7200ULL*4ULL)

// ---- output layout (float elements) ----
#define OBIN 0
#define ORES (NB*KSEL*5)           // 81920
#define OBOX (ORES + NB*KSEL)      // 98304
#define OCLS (OBOX + NB*KSEL*7)    // 212992

// ctrl per batch (16 uint32): [0]=P(hi16) [1]=count_gt_P [2]=T(full bits) [3]=cand_count

// monotonic float -> sortable uint (ascending); same order as sigmoid(max) in f64
__device__ __forceinline__ uint32_t key_of(float mx) {
    uint32_t b = __float_as_uint(mx);
    uint32_t mask = ((int32_t)b >> 31) | 0x80000000u;
    return b ^ mask;
}

// ---------------- weights prep: fold BN into conv weights ----------------
__global__ __launch_bounds__(256) void k_prep(
    const float* __restrict__ c1w, const float* __restrict__ g1, const float* __restrict__ b1,
    const float* __restrict__ m1, const float* __restrict__ v1,
    const float* __restrict__ c2w, const float* __restrict__ g2, const float* __restrict__ b2,
    const float* __restrict__ m2, const float* __restrict__ v2,
    float* __restrict__ wf)
{
    int t = blockIdx.x * 256 + threadIdx.x;
    if (t < 960) {                       // w1f [o][i][tap] same layout as conv1_w
        int o = t / 30;
        float inv = g1[o] / sqrtf(v1[o] + 1e-5f);
        wf[t] = c1w[t] * inv;
    } else if (t < 992) {                // b1f
        int o = t - 960;
        float inv = g1[o] / sqrtf(v1[o] + 1e-5f);
        wf[960 + o] = b1[o] - m1[o] * inv;
    } else if (t < 7136) {               // w2f [i][o][tap]
        int e = t - 992;
        int i = e / 192, r = e % 192, o = r / 3, tap = r % 3;
        float inv = g2[o] / sqrtf(v2[o] + 1e-5f);
        wf[992 + e] = c2w[(o * 32 + i) * 3 + tap] * inv;
    } else if (t < 7200) {               // b2f
        int o = t - 7136;
        float inv = g2[o] / sqrtf(v2[o] + 1e-5f);
        wf[7136 + o] = b2[o] - m2[o] * inv;
    }
}

// ---------------- score key + hi16 histogram ----------------
// LDS window: key hi16 in [0xB800, 0xC800) — 4096 bins (mx in [~3e-5, 3.4e10))
__global__ __launch_bounds__(256) void k_score_hist(
    const float* __restrict__ cls, uint32_t* __restrict__ bits, uint32_t* __restrict__ hist1)
{
    __shared__ uint32_t lh[4096];
    for (int i = threadIdx.x; i < 4096; i += 256) lh[i] = 0;
    __syncthreads();
    int b = blockIdx.x >> 8;
    int blk = blockIdx.x & 255;
    int chunk = blk * 256 + threadIdx.x;   // [0, 65536)
    int n0 = chunk * 4;
    const float4* p = (const float4*)(cls + ((size_t)b * NPTS + (size_t)n0) * 3);
    float4 v0 = p[0], v1 = p[1], v2 = p[2];
    float m0 = fmaxf(fmaxf(v0.x, v0.y), v0.z);
    float m1 = fmaxf(fmaxf(v0.w, v1.x), v1.y);
    float m2 = fmaxf(fmaxf(v1.z, v1.w), v2.x);
    float m3 = fmaxf(fmaxf(v2.y, v2.z), v2.w);
    uint4 o;
    o.x = key_of(m0); o.y = key_of(m1); o.z = key_of(m2); o.w = key_of(m3);
    ((uint4*)(bits + (size_t)b * NPTS))[chunk] = o;
    uint32_t bs[4] = {o.x, o.y, o.z, o.w};
    #pragma unroll
    for (int i = 0; i < 4; ++i) {
        uint32_t hi = bs[i] >> 16;
        if (hi >= 0xB800u && hi < 0xC800u) atomicAdd(&lh[hi - 0xB800u], 1u);
        else                               atomicAdd(&hist1[b * 65536 + hi], 1u);
    }
    __syncthreads();
    for (int i = threadIdx.x; i < 4096; i += 256)
        if (lh[i]) atomicAdd(&hist1[b * 65536 + 0xB800 + i], lh[i]);
}

// ---------------- scan histogram from top to find threshold digit ----------------
__global__ __launch_bounds__(256) void k_scan(
    const uint32_t* __restrict__ hist, uint32_t* __restrict__ ctrl, int stage)
{
    int b = blockIdx.x;
    const uint32_t* h = hist + (size_t)b * 65536;
    __shared__ uint32_t part[256];
    __shared__ uint32_t binsS[256];
    __shared__ int segS;
    __shared__ uint32_t runS;
    uint32_t K = (stage == 0) ? (uint32_t)KSEL : (uint32_t)KSEL - ctrl[b * 16 + 1];
    uint32_t sum = 0;
    int base = threadIdx.x * 256;
    for (int i = 0; i < 256; ++i) sum += h[base + i];
    part[threadIdx.x] = sum;
    __syncthreads();
    if (threadIdx.x == 0) {
        uint32_t running = 0; int seg = 0;
        for (int t = 255; t >= 0; --t) {
            if (running + part[t] >= K) { seg = t; break; }
            running += part[t];
        }
        segS = seg; runS = running;
    }
    __syncthreads();
    binsS[threadIdx.x] = h[segS * 256 + threadIdx.x];
    __syncthreads();
    if (threadIdx.x == 0) {
        uint32_t running = runS;
        for (int i = 255; i >= 0; --i) {
            running += binsS[i];
            if (running >= K) {
                uint32_t bin = (uint32_t)(segS * 256 + i);
                if (stage == 0) {
                    ctrl[b * 16 + 0] = bin;                      // P
                    ctrl[b * 16 + 1] = running - binsS[i];       // count strictly above P
                } else {
                    ctrl[b * 16 + 2] = (ctrl[b * 16 + 0] << 16) | bin;  // exact T
                }
                break;
            }
        }
    }
}

// ---------------- lo16 histogram for elements with hi16 == P ----------------
__global__ __launch_bounds__(256) void k_hist2(
    const uint32_t* __restrict__ bits, const uint32_t* __restrict__ ctrl, uint32_t* __restrict__ hist2)
{
    int b = blockIdx.x >> 8;
    int chunk = (blockIdx.x & 255) * 256 + threadIdx.x;
    uint32_t P = ctrl[b * 16 + 0];
    uint4 v = ((const uint4*)(bits + (size_t)b * NPTS))[chunk];
    if ((v.x >> 16) == P) atomicAdd(&hist2[b * 65536 + (v.x & 0xFFFFu)], 1u);
    if ((v.y >> 16) == P) atomicAdd(&hist2[b * 65536 + (v.y & 0xFFFFu)], 1u);
    if ((v.z >> 16) == P) atomicAdd(&hist2[b * 65536 + (v.z & 0xFFFFu)], 1u);
    if ((v.w >> 16) == P) atomicAdd(&hist2[b * 65536 + (v.w & 0xFFFFu)], 1u);
}

// ---------------- compact candidates (key >= T) ----------------
__global__ __launch_bounds__(256) void k_compact(
    const uint32_t* __restrict__ bits, uint32_t* __restrict__ ctrl, uint64_t* __restrict__ cand)
{
    int b = blockIdx.x >> 8;
    int chunk = (blockIdx.x & 255) * 256 + threadIdx.x;
    uint32_t T = ctrl[b * 16 + 2];
    uint4 v = ((const uint4*)(bits + (size_t)b * NPTS))[chunk];
    uint32_t n0 = (uint32_t)chunk * 4;
    uint32_t bs[4] = {v.x, v.y, v.z, v.w};
    #pragma unroll
    for (int i = 0; i < 4; ++i) {
        if (bs[i] >= T) {
            uint32_t pos = atomicAdd(&ctrl[b * 16 + 3], 1u);
            if (pos < CAP)
                cand[(size_t)b * CAP + pos] = ((uint64_t)(~bs[i]) << 32) | (uint64_t)(n0 + i);
        }
    }
}

// ---------------- rank (key desc, index asc) + gather ----------------
__global__ __launch_bounds__(256) void k_rank(
    const uint64_t* __restrict__ cand, const uint32_t* __restrict__ ctrl,
    const float* __restrict__ box, const float* __restrict__ cls, float* __restrict__ out)
{
    __shared__ uint64_t keys[CAP];
    int b = blockIdx.x >> 4;            // 16 blocks per batch
    int blk = blockIdx.x & 15;
    uint32_t C = ctrl[b * 16 + 3];
    if (C > CAP) C = CAP;
    for (uint32_t i = threadIdx.x; i < C; i += 256) keys[i] = cand[(size_t)b * CAP + i];
    __syncthreads();
    for (uint32_t item = (uint32_t)(blk * 256) + threadIdx.x; item < C; item += 4096) {
        uint64_t me = keys[item];
        uint32_t rank = 0;
        #pragma unroll 4
        for (uint32_t j = 0; j < C; ++j) rank += (keys[j] < me) ? 1u : 0u;
        if (rank < KSEL) {
            uint32_t n = (uint32_t)me;
            const float* bp = box + ((size_t)b * NPTS + n) * 7;
            float* ob = out + OBOX + ((size_t)b * KSEL + rank) * 7;
            #pragma unroll
            for (int c = 0; c < 7; ++c) ob[c] = bp[c];
            const float* cp = cls + ((size_t)b * NPTS + n) * 3;
            float* oc = out + OCLS + ((size_t)b * KSEL + rank) * 3;
            #pragma unroll
            for (int c = 0; c < 3; ++c) oc[c] = cp[c];
        }
    }
}

// ---------------- fused conv1+bn+relu+conv2+bn+relu+heads ----------------
__global__ __launch_bounds__(256) void k_conv(
    const float* __restrict__ wf,
    const float* __restrict__ binw, const float* __restrict__ binb,
    const float* __restrict__ resw, const float* __restrict__ resb,
    float* __restrict__ out)
{
    int b = blockIdx.y;
    int tile = blockIdx.x * 256;
    __shared__ float xin[10][264];       // global positions [tile-2, tile+257]
    __shared__ float x1s[32][264];       // global positions [tile-1, tile+256]
    const float* boxsel = out + OBOX + (size_t)b * KSEL * 7;
    const float* clssel = out + OCLS + (size_t)b * KSEL * 3;

    for (int t = threadIdx.x; t < 2600; t += 256) {
        int c = t / 260, k = t % 260;
        int g = tile + k - 2;
        float val = 0.f;
        if (g >= 0 && g < KSEL) val = (c < 7) ? boxsel[g * 7 + c] : clssel[g * 3 + (c - 7)];
        xin[c][k] = val;
    }
    __syncthreads();

    const float* w1f = wf;
    const float* b1f = wf + 960;
    for (int k1 = threadIdx.x; k1 < 258; k1 += 256) {
        int g1 = tile + k1 - 1;          // global position of this x1 column
        if (g1 < 0 || g1 >= KSEL) {
            // conv2's zero padding: x1 outside [0, K) is ZERO, not conv1(padded x)
            #pragma unroll
            for (int o = 0; o < 32; ++o) x1s[o][k1] = 0.f;
        } else {
            float xr[30];
            #pragma unroll
            for (int i = 0; i < 10; ++i) {
                xr[i * 3 + 0] = xin[i][k1 + 0];
                xr[i * 3 + 1] = xin[i][k1 + 1];
                xr[i * 3 + 2] = xin[i][k1 + 2];
            }
            #pragma unroll
            for (int o = 0; o < 32; ++o) {
                float acc = b1f[o];
                #pragma unroll
                for (int q = 0; q < 30; ++q) acc = fmaf(w1f[o * 30 + q], xr[q], acc);
                x1s[o][k1] = fmaxf(acc, 0.f);
            }
        }
    }
    __syncthreads();

    const float* w2f = wf + 992;         // [i][o][tap]
    const float* b2f = wf + 7136;
    int p = threadIdx.x;
    float acc[64];
    #pragma unroll
    for (int o = 0; o < 64; ++o) acc[o] = b2f[o];
    for (int i = 0; i < 32; ++i) {
        float a0 = x1s[i][p], a1 = x1s[i][p + 1], a2 = x1s[i][p + 2];
        const float* w = w2f + i * 192;
        #pragma unroll
        for (int o = 0; o < 64; ++o) {
            acc[o] = fmaf(w[o * 3 + 0], a0, acc[o]);
            acc[o] = fmaf(w[o * 3 + 1], a1, acc[o]);
            acc[o] = fmaf(w[o * 3 + 2], a2, acc[o]);
        }
    }
    #pragma unroll
    for (int o = 0; o < 64; ++o) acc[o] = fmaxf(acc[o], 0.f);

    size_t g = (size_t)b * KSEL + (size_t)(tile + p);
    #pragma unroll
    for (int j = 0; j < 5; ++j) {
        float s = binb[j];
        #pragma unroll
        for (int o = 0; o < 64; ++o) s = fmaf(binw[j * 64 + o], acc[o], s);
        out[OBIN + g * 5 + j] = s;
    }
    float r = resb[0];
    #pragma unroll
    for (int o = 0; o < 64; ++o) r = fmaf(resw[o], acc[o], r);
    out[ORES + g] = r;
}

extern "C" void kernel_launch(void* const* d_in, const int* in_sizes, int n_in,
                              void* d_out, int out_size, void* d_ws, size_t ws_size,
                              hipStream_t stream)
{
    const float* box  = (const float*)d_in[0];
    const float* cls  = (const float*)d_in[1];
    const float* c1w  = (const float*)d_in[2];
    const float* g1   = (const float*)d_in[3];
    const float* b1   = (const float*)d_in[4];
    const float* m1   = (const float*)d_in[5];
    const float* v1   = (const float*)d_in[6];
    const float* c2w  = (const float*)d_in[7];
    const float* g2   = (const float*)d_in[8];
    const float* b2   = (const float*)d_in[9];
    const float* m2   = (const float*)d_in[10];
    const float* v2   = (const float*)d_in[11];
    const float* binw = (const float*)d_in[12];
    const float* binb = (const float*)d_in[13];
    const float* resw = (const float*)d_in[14];
    const float* resb = (const float*)d_in[15];
    float* out = (float*)d_out;
    char* ws = (char*)d_ws;
    if (ws_size < WS_NEEDED) return;

    uint32_t* bits  = (uint32_t*)(ws + OFF_BITS);
    uint32_t* hist1 = (uint32_t*)(ws + OFF_H1);
    uint32_t* hist2 = (uint32_t*)(ws + OFF_H2);
    uint32_t* ctrl  = (uint32_t*)(ws + OFF_CTRL);
    uint64_t* cand  = (uint64_t*)(ws + OFF_CAND);
    float*    wf    = (float*)(ws + OFF_WF);

    hipMemsetAsync(ws + OFF_H1, 0, (size_t)(OFF_CTRL + 1024ULL - OFF_H1), stream);
    k_prep<<<29, 256, 0, stream>>>(c1w, g1, b1, m1, v1, c2w, g2, b2, m2, v2, wf);
    k_score_hist<<<1024, 256, 0, stream>>>(cls, bits, hist1);
    k_scan<<<4, 256, 0, stream>>>(hist1, ctrl, 0);
    k_hist2<<<1024, 256, 0, stream>>>(bits, ctrl, hist2);
    k_scan<<<4, 256, 0, stream>>>(hist2, ctrl, 1);
    k_compact<<<1024, 256, 0, stream>>>(bits, ctrl, cand);
    k_rank<<<64, 256, 0, stream>>>(cand, ctrl, box, cls, out);
    k_conv<<<dim3(16, 4), 256, 0, stream>>>(wf, binw, binb, resw, resb, out);
}

// Round 4
// 217.930 us; speedup vs baseline: 1.4056x; 1.4056x over previous
//
#include <hip/hip_runtime.h>
#include <stdint.h>
#include <math.h>

#define NPTS 262144
#define NB 4
#define KSEL 4096
#define CAP 8192
#define SLICES 8
#define SLICE_LEN (CAP / SLICES)   // 1024 keys, 8 KB LDS

// ---- workspace layout (bytes) ----
#define OFF_BITS  0ULL
#define OFF_H1    (4ULL*NPTS*NB)                       // 4 MB
#define OFF_CTRL  (OFF_H1 + 4ULL*65536*NB)             // +1 MB
#define OFF_GRANK (OFF_CTRL + 1024ULL)
#define OFF_CAND  (OFF_GRANK + 4ULL*CAP*NB)            // 128 KB grank
#define OFF_WF    (OFF_CAND + 8ULL*CAP*NB)             // 256 KB cand
#define WS_NEEDED (OFF_WF + 7200ULL*4ULL)
#define MEMSET_LEN (OFF_CAND - OFF_H1)                 // hist1+ctrl+grank contiguous

// ---- output layout (float elements) ----
#define OBIN 0
#define ORES (NB*KSEL*5)           // 81920
#define OBOX (ORES + NB*KSEL)      // 98304
#define OCLS (OBOX + NB*KSEL*7)    // 212992

// ctrl per batch (16 uint32): [0]=P(hi16) [3]=cand_count

// monotonic float -> sortable uint (ascending)
__device__ __forceinline__ uint32_t key_of(float mx) {
    uint32_t b = __float_as_uint(mx);
    uint32_t mask = ((int32_t)b >> 31) | 0x80000000u;
    return b ^ mask;
}

// ---------------- weights prep: fold BN into conv weights ----------------
__global__ __launch_bounds__(256) void k_prep(
    const float* __restrict__ c1w, const float* __restrict__ g1, const float* __restrict__ b1,
    const float* __restrict__ m1, const float* __restrict__ v1,
    const float* __restrict__ c2w, const float* __restrict__ g2, const float* __restrict__ b2,
    const float* __restrict__ m2, const float* __restrict__ v2,
    float* __restrict__ wf)
{
    int t = blockIdx.x * 256 + threadIdx.x;
    if (t < 960) {                       // w1f [o][i][tap]
        int o = t / 30;
        float inv = g1[o] / sqrtf(v1[o] + 1e-5f);
        wf[t] = c1w[t] * inv;
    } else if (t < 992) {                // b1f
        int o = t - 960;
        float inv = g1[o] / sqrtf(v1[o] + 1e-5f);
        wf[960 + o] = b1[o] - m1[o] * inv;
    } else if (t < 7136) {               // w2f [i][o][tap]
        int e = t - 992;
        int i = e / 192, r = e % 192, o = r / 3, tap = r % 3;
        float inv = g2[o] / sqrtf(v2[o] + 1e-5f);
        wf[992 + e] = c2w[(o * 32 + i) * 3 + tap] * inv;
    } else if (t < 7200) {               // b2f
        int o = t - 7136;
        float inv = g2[o] / sqrtf(v2[o] + 1e-5f);
        wf[7136 + o] = b2[o] - m2[o] * inv;
    }
}

// ---------------- score key + hi16 histogram (dual LDS window) ----------------
// window A: hi16 in [0xB800, 0xC800)  positives |mx| in [2^-15, 2^16)
// window B: hi16 in [0x3800, 0x4800)  negatives
__global__ __launch_bounds__(256) void k_score_hist(
    const float* __restrict__ cls, uint32_t* __restrict__ bits, uint32_t* __restrict__ hist1)
{
    __shared__ uint32_t lh[8192];
    for (int i = threadIdx.x; i < 8192; i += 256) lh[i] = 0;
    __syncthreads();
    int b = blockIdx.x >> 8;
    int blk = blockIdx.x & 255;
    int chunk = blk * 256 + threadIdx.x;   // [0, 65536)
    const float4* p = (const float4*)(cls + ((size_t)b * NPTS + (size_t)chunk * 4) * 3);
    float4 v0 = p[0], v1 = p[1], v2 = p[2];
    float m0 = fmaxf(fmaxf(v0.x, v0.y), v0.z);
    float m1 = fmaxf(fmaxf(v0.w, v1.x), v1.y);
    float m2 = fmaxf(fmaxf(v1.z, v1.w), v2.x);
    float m3 = fmaxf(fmaxf(v2.y, v2.z), v2.w);
    uint4 o;
    o.x = key_of(m0); o.y = key_of(m1); o.z = key_of(m2); o.w = key_of(m3);
    ((uint4*)(bits + (size_t)b * NPTS))[chunk] = o;
    uint32_t bs[4] = {o.x, o.y, o.z, o.w};
    #pragma unroll
    for (int i = 0; i < 4; ++i) {
        uint32_t hi = bs[i] >> 16;
        uint32_t dA = hi - 0xB800u, dB = hi - 0x3800u;
        if (dA < 0x1000u)      atomicAdd(&lh[dA], 1u);
        else if (dB < 0x1000u) atomicAdd(&lh[4096 + dB], 1u);
        else                   atomicAdd(&hist1[b * 65536 + hi], 1u);
    }
    __syncthreads();
    for (int i = threadIdx.x; i < 8192; i += 256) {
        uint32_t c = lh[i];
        if (c) {
            uint32_t bin = (i < 4096) ? (0xB800u + i) : (0x3800u + (i - 4096));
            atomicAdd(&hist1[b * 65536 + bin], c);
        }
    }
}

// ---------------- find P: hi16 bin where cumulative-from-top reaches KSEL ----------------
__global__ __launch_bounds__(256) void k_scan(
    const uint32_t* __restrict__ hist, uint32_t* __restrict__ ctrl)
{
    int b = blockIdx.x;
    const uint32_t* h = hist + (size_t)b * 65536;
    __shared__ uint32_t part[256];
    __shared__ uint32_t binsS[256];
    __shared__ int segS;
    __shared__ uint32_t runS;
    int w = threadIdx.x >> 6, lane = threadIdx.x & 63;
    // coalesced segment sums: wave w handles segments w, w+4, ...
    for (int seg = w; seg < 256; seg += 4) {
        uint4 v = ((const uint4*)(h + seg * 256))[lane];   // 64 lanes x 16B = 1 KB
        uint32_t s = v.x + v.y + v.z + v.w;
        #pragma unroll
        for (int off = 32; off; off >>= 1) s += __shfl_xor(s, off, 64);
        if (lane == 0) part[seg] = s;
    }
    __syncthreads();
    if (threadIdx.x == 0) {
        uint32_t running = 0; int seg = 0;
        for (int t = 255; t >= 0; --t) {
            if (running + part[t] >= (uint32_t)KSEL) { seg = t; break; }
            running += part[t];
        }
        segS = seg; runS = running;
    }
    __syncthreads();
    binsS[threadIdx.x] = h[segS * 256 + threadIdx.x];
    __syncthreads();
    if (threadIdx.x == 0) {
        uint32_t running = runS;
        for (int i = 255; i >= 0; --i) {
            running += binsS[i];
            if (running >= (uint32_t)KSEL) {
                ctrl[b * 16 + 0] = (uint32_t)(segS * 256 + i);   // P
                break;
            }
        }
    }
}

// ---------------- compact candidate superset (hi16 >= P) ----------------
__global__ __launch_bounds__(256) void k_compact(
    const uint32_t* __restrict__ bits, uint32_t* __restrict__ ctrl, uint64_t* __restrict__ cand)
{
    int b = blockIdx.x >> 8;
    int chunk = (blockIdx.x & 255) * 256 + threadIdx.x;
    uint32_t P = ctrl[b * 16 + 0];
    uint4 v = ((const uint4*)(bits + (size_t)b * NPTS))[chunk];
    uint32_t n0 = (uint32_t)chunk * 4;
    uint32_t bs[4] = {v.x, v.y, v.z, v.w};
    #pragma unroll
    for (int i = 0; i < 4; ++i) {
        if ((bs[i] >> 16) >= P) {
            uint32_t pos = atomicAdd(&ctrl[b * 16 + 3], 1u);
            if (pos < CAP)
                cand[(size_t)b * CAP + pos] = ((uint64_t)(~bs[i]) << 32) | (uint64_t)(n0 + i);
        }
    }
}

// ---------------- partial ranks over key slices ----------------
__global__ __launch_bounds__(256) void k_rank1(
    const uint64_t* __restrict__ cand, const uint32_t* __restrict__ ctrl,
    uint32_t* __restrict__ grank)
{
    __shared__ uint64_t keys[SLICE_LEN];
    int b = blockIdx.z;
    uint32_t C = ctrl[b * 16 + 3];
    if (C > CAP) C = CAP;
    uint32_t k0 = blockIdx.y * SLICE_LEN;
    if (k0 >= C) return;                         // uniform per block
    uint32_t nk = C - k0; if (nk > SLICE_LEN) nk = SLICE_LEN;
    for (uint32_t i = threadIdx.x; i < nk; i += 256)
        keys[i] = cand[(size_t)b * CAP + k0 + i];
    __syncthreads();
    uint32_t item = blockIdx.x * 256 + threadIdx.x;
    if (item >= C) return;
    uint64_t me = cand[(size_t)b * CAP + item];
    uint32_t r = 0;
    #pragma unroll 16
    for (uint32_t i = 0; i < nk; ++i) r += (keys[i] < me) ? 1u : 0u;
    atomicAdd(&grank[b * CAP + item], r);
}

// ---------------- gather by rank ----------------
__global__ __launch_bounds__(256) void k_rank2(
    const uint64_t* __restrict__ cand, const uint32_t* __restrict__ ctrl,
    const uint32_t* __restrict__ grank,
    const float* __restrict__ box, const float* __restrict__ cls, float* __restrict__ out)
{
    int b = blockIdx.y;
    uint32_t C = ctrl[b * 16 + 3];
    if (C > CAP) C = CAP;
    uint32_t item = blockIdx.x * 256 + threadIdx.x;
    if (item >= C) return;
    uint64_t me = cand[(size_t)b * CAP + item];
    uint32_t rank = grank[b * CAP + item];
    if (rank < KSEL) {
        uint32_t n = (uint32_t)me;
        const float* bp = box + ((size_t)b * NPTS + n) * 7;
        float* ob = out + OBOX + ((size_t)b * KSEL + rank) * 7;
        #pragma unroll
        for (int c = 0; c < 7; ++c) ob[c] = bp[c];
        const float* cp = cls + ((size_t)b * NPTS + n) * 3;
        float* oc = out + OCLS + ((size_t)b * KSEL + rank) * 3;
        #pragma unroll
        for (int c = 0; c < 3; ++c) oc[c] = cp[c];
    }
}

// ---------------- fused conv1+bn+relu+conv2+bn+relu+heads ----------------
__global__ __launch_bounds__(256) void k_conv(
    const float* __restrict__ wf,
    const float* __restrict__ binw, const float* __restrict__ binb,
    const float* __restrict__ resw, const float* __restrict__ resb,
    float* __restrict__ out)
{
    int b = blockIdx.y;
    int tile = blockIdx.x * 256;
    __shared__ float xin[10][264];       // global positions [tile-2, tile+257]
    __shared__ float x1s[32][264];       // global positions [tile-1, tile+256]
    const float* boxsel = out + OBOX + (size_t)b * KSEL * 7;
    const float* clssel = out + OCLS + (size_t)b * KSEL * 3;

    for (int t = threadIdx.x; t < 2600; t += 256) {
        int c = t / 260, k = t % 260;
        int g = tile + k - 2;
        float val = 0.f;
        if (g >= 0 && g < KSEL) val = (c < 7) ? boxsel[g * 7 + c] : clssel[g * 3 + (c - 7)];
        xin[c][k] = val;
    }
    __syncthreads();

    const float* w1f = wf;
    const float* b1f = wf + 960;
    for (int k1 = threadIdx.x; k1 < 258; k1 += 256) {
        int g1 = tile + k1 - 1;
        if (g1 < 0 || g1 >= KSEL) {      // conv2 zero padding: x1 outside [0,K) is ZERO
            #pragma unroll
            for (int o = 0; o < 32; ++o) x1s[o][k1] = 0.f;
        } else {
            float xr[30];
            #pragma unroll
            for (int i = 0; i < 10; ++i) {
                xr[i * 3 + 0] = xin[i][k1 + 0];
                xr[i * 3 + 1] = xin[i][k1 + 1];
                xr[i * 3 + 2] = xin[i][k1 + 2];
            }
            #pragma unroll
            for (int o = 0; o < 32; ++o) {
                float acc = b1f[o];
                #pragma unroll
                for (int q = 0; q < 30; ++q) acc = fmaf(w1f[o * 30 + q], xr[q], acc);
                x1s[o][k1] = fmaxf(acc, 0.f);
            }
        }
    }
    __syncthreads();

    const float* w2f = wf + 992;         // [i][o][tap]
    const float* b2f = wf + 7136;
    int p = threadIdx.x;
    float acc[64];
    #pragma unroll
    for (int o = 0; o < 64; ++o) acc[o] = b2f[o];
    for (int i = 0; i < 32; ++i) {
        float a0 = x1s[i][p], a1 = x1s[i][p + 1], a2 = x1s[i][p + 2];
        const float* w = w2f + i * 192;
        #pragma unroll
        for (int o = 0; o < 64; ++o) {
            acc[o] = fmaf(w[o * 3 + 0], a0, acc[o]);
            acc[o] = fmaf(w[o * 3 + 1], a1, acc[o]);
            acc[o] = fmaf(w[o * 3 + 2], a2, acc[o]);
        }
    }
    #pragma unroll
    for (int o = 0; o < 64; ++o) acc[o] = fmaxf(acc[o], 0.f);

    size_t g = (size_t)b * KSEL + (size_t)(tile + p);
    #pragma unroll
    for (int j = 0; j < 5; ++j) {
        float s = binb[j];
        #pragma unroll
        for (int o = 0; o < 64; ++o) s = fmaf(binw[j * 64 + o], acc[o], s);
        out[OBIN + g * 5 + j] = s;
    }
    float r = resb[0];
    #pragma unroll
    for (int o = 0; o < 64; ++o) r = fmaf(resw[o], acc[o], r);
    out[ORES + g] = r;
}

extern "C" void kernel_launch(void* const* d_in, const int* in_sizes, int n_in,
                              void* d_out, int out_size, void* d_ws, size_t ws_size,
                              hipStream_t stream)
{
    const float* box  = (const float*)d_in[0];
    const float* cls  = (const float*)d_in[1];
    const float* c1w  = (const float*)d_in[2];
    const float* g1   = (const float*)d_in[3];
    const float* b1   = (const float*)d_in[4];
    const float* m1   = (const float*)d_in[5];
    const float* v1   = (const float*)d_in[6];
    const float* c2w  = (const float*)d_in[7];
    const float* g2   = (const float*)d_in[8];
    const float* b2   = (const float*)d_in[9];
    const float* m2   = (const float*)d_in[10];
    const float* v2   = (const float*)d_in[11];
    const float* binw = (const float*)d_in[12];
    const float* binb = (const float*)d_in[13];
    const float* resw = (const float*)d_in[14];
    const float* resb = (const float*)d_in[15];
    float* out = (float*)d_out;
    char* ws = (char*)d_ws;
    if (ws_size < WS_NEEDED) return;

    uint32_t* bits  = (uint32_t*)(ws + OFF_BITS);
    uint32_t* hist1 = (uint32_t*)(ws + OFF_H1);
    uint32_t* ctrl  = (uint32_t*)(ws + OFF_CTRL);
    uint32_t* grank = (uint32_t*)(ws + OFF_GRANK);
    uint64_t* cand  = (uint64_t*)(ws + OFF_CAND);
    float*    wf    = (float*)(ws + OFF_WF);

    hipMemsetAsync(ws + OFF_H1, 0, (size_t)MEMSET_LEN, stream);
    k_prep<<<29, 256, 0, stream>>>(c1w, g1, b1, m1, v1, c2w, g2, b2, m2, v2, wf);
    k_score_hist<<<1024, 256, 0, stream>>>(cls, bits, hist1);
    k_scan<<<4, 256, 0, stream>>>(hist1, ctrl);
    k_compact<<<1024, 256, 0, stream>>>(bits, ctrl, cand);
    k_rank1<<<dim3(CAP / 256, SLICES, NB), 256, 0, stream>>>(cand, ctrl, grank);
    k_rank2<<<dim3(CAP / 256, NB), 256, 0, stream>>>(cand, ctrl, grank, box, cls, out);
    k_conv<<<dim3(16, 4), 256, 0, stream>>>(wf, binw, binb, resw, resb, out);
}

// Round 5
// 164.045 us; speedup vs baseline: 1.8673x; 1.3285x over previous
//
#include <hip/hip_runtime.h>
#include <stdint.h>

#define NPTS 262144
#define NB 4
#define KSEL 4096
#define CAP 8192
#define SLICES 8
#define SLICE_LEN (CAP / SLICES)   // 1024 keys, 8 KB LDS

// ---- workspace layout (bytes) ----
#define OFF_BITS  0ULL
#define OFF_H8    (4ULL*NPTS*NB)                       // 4 MB
#define OFF_H16   (OFF_H8 + 4ULL*256*NB)               // +4 KB
#define OFF_CTRL  (OFF_H16 + 4ULL*65536*NB)            // +1 MB
#define OFF_GRANK (OFF_CTRL + 1024ULL)
#define OFF_CAND  (OFF_GRANK + 4ULL*CAP*NB)            // 128 KB grank
#define WS_NEEDED (OFF_CAND + 8ULL*CAP*NB)             // +256 KB cand
#define MEMSET_LEN (OFF_CAND - OFF_H8)                 // h8+h16+ctrl+grank

// ---- output layout (float elements) ----
#define OBIN 0
#define ORES (NB*KSEL*5)           // 81920
#define OBOX (ORES + NB*KSEL)      // 98304
#define OCLS (OBOX + NB*KSEL*7)    // 212992

// ctrl per batch (16 u32): [0]=P8 [1]=count_above_P8 [2]=T24 [3]=cand_count

__device__ __forceinline__ uint32_t key_of(float mx) {
    uint32_t b = __float_as_uint(mx);
    uint32_t mask = ((int32_t)b >> 31) | 0x80000000u;
    return b ^ mask;
}

// ---------------- keys + hi8 histogram ----------------
__global__ __launch_bounds__(256) void k_score_hist(
    const float* __restrict__ cls, uint32_t* __restrict__ bits, uint32_t* __restrict__ h8)
{
    __shared__ uint32_t lh[8][256];
    for (int i = threadIdx.x; i < 2048; i += 256) ((uint32_t*)lh)[i] = 0;
    __syncthreads();
    int b = blockIdx.y;
    int sub = threadIdx.x >> 5;          // 8 sub-hists (half-wave granularity)
    for (int it = 0; it < 4; ++it) {
        int chunk = blockIdx.x * 1024 + it * 256 + threadIdx.x;    // uint4-chunk in [0,65536)
        const float4* p = (const float4*)(cls + ((size_t)b * NPTS + (size_t)chunk * 4) * 3);
        float4 v0 = p[0], v1 = p[1], v2 = p[2];
        uint4 o;
        o.x = key_of(fmaxf(fmaxf(v0.x, v0.y), v0.z));
        o.y = key_of(fmaxf(fmaxf(v0.w, v1.x), v1.y));
        o.z = key_of(fmaxf(fmaxf(v1.z, v1.w), v2.x));
        o.w = key_of(fmaxf(fmaxf(v2.y, v2.z), v2.w));
        ((uint4*)(bits + (size_t)b * NPTS))[chunk] = o;
        atomicAdd(&lh[sub][o.x >> 24], 1u);
        atomicAdd(&lh[sub][o.y >> 24], 1u);
        atomicAdd(&lh[sub][o.z >> 24], 1u);
        atomicAdd(&lh[sub][o.w >> 24], 1u);
    }
    __syncthreads();
    int i = threadIdx.x;                 // one bin per thread
    uint32_t c = 0;
    #pragma unroll
    for (int s = 0; s < 8; ++s) c += lh[s][i];
    if (c) atomicAdd(&h8[b * 256 + i], c);
}

// ---------------- find P8 ----------------
__global__ __launch_bounds__(256) void k_scan8(
    const uint32_t* __restrict__ h8, uint32_t* __restrict__ ctrl)
{
    __shared__ uint32_t s[256];
    int b = blockIdx.x;
    s[threadIdx.x] = h8[b * 256 + threadIdx.x];
    __syncthreads();
    if (threadIdx.x == 0) {
        uint32_t running = 0;
        for (int i = 255; i >= 0; --i) {
            if (running + s[i] >= (uint32_t)KSEL) {
                ctrl[b * 16 + 0] = (uint32_t)i;      // P8
                ctrl[b * 16 + 1] = running;          // strictly above
                break;
            }
            running += s[i];
        }
    }
}

// ---------------- mid16 histogram of the P8 bucket ----------------
__global__ __launch_bounds__(256) void k_hist16(
    const uint32_t* __restrict__ bits, const uint32_t* __restrict__ ctrl, uint32_t* __restrict__ h16)
{
    int b = blockIdx.y;
    uint32_t P8 = ctrl[b * 16 + 0];
    for (int it = 0; it < 4; ++it) {
        int chunk = blockIdx.x * 1024 + it * 256 + threadIdx.x;
        uint4 v = ((const uint4*)(bits + (size_t)b * NPTS))[chunk];
        if ((v.x >> 24) == P8) atomicAdd(&h16[b * 65536 + ((v.x >> 8) & 0xFFFFu)], 1u);
        if ((v.y >> 24) == P8) atomicAdd(&h16[b * 65536 + ((v.y >> 8) & 0xFFFFu)], 1u);
        if ((v.z >> 24) == P8) atomicAdd(&h16[b * 65536 + ((v.z >> 8) & 0xFFFFu)], 1u);
        if ((v.w >> 24) == P8) atomicAdd(&h16[b * 65536 + ((v.w >> 8) & 0xFFFFu)], 1u);
    }
}

// ---------------- find T24 (coalesced wave-parallel scan of 64K bins) ----------------
__global__ __launch_bounds__(256) void k_scan16(
    const uint32_t* __restrict__ h16, uint32_t* __restrict__ ctrl)
{
    int b = blockIdx.x;
    const uint32_t* h = h16 + (size_t)b * 65536;
    __shared__ uint32_t part[256];
    __shared__ uint32_t binsS[256];
    __shared__ int segS;
    __shared__ uint32_t runS;
    uint32_t K = (uint32_t)KSEL - ctrl[b * 16 + 1];
    int w = threadIdx.x >> 6, lane = threadIdx.x & 63;
    for (int seg = w; seg < 256; seg += 4) {
        uint4 v = ((const uint4*)(h + seg * 256))[lane];
        uint32_t s = v.x + v.y + v.z + v.w;
        #pragma unroll
        for (int off = 32; off; off >>= 1) s += __shfl_xor(s, off, 64);
        if (lane == 0) part[seg] = s;
    }
    __syncthreads();
    if (threadIdx.x == 0) {
        uint32_t running = 0; int seg = 0;
        for (int t = 255; t >= 0; --t) {
            if (running + part[t] >= K) { seg = t; break; }
            running += part[t];
        }
        segS = seg; runS = running;
    }
    __syncthreads();
    binsS[threadIdx.x] = h[segS * 256 + threadIdx.x];
    __syncthreads();
    if (threadIdx.x == 0) {
        uint32_t running = runS;
        for (int i = 255; i >= 0; --i) {
            running += binsS[i];
            if (running >= K) {
                ctrl[b * 16 + 2] = (ctrl[b * 16 + 0] << 16) | (uint32_t)(segS * 256 + i);
                break;
            }
        }
    }
}

// ---------------- compact superset (key>>8 >= T24), wave-aggregated atomics ----------------
__global__ __launch_bounds__(256) void k_compact(
    const uint32_t* __restrict__ bits, uint32_t* __restrict__ ctrl, uint64_t* __restrict__ cand)
{
    int b = blockIdx.y;
    uint32_t T = ctrl[b * 16 + 2];
    int lane = threadIdx.x & 63;
    uint64_t lmask = (1ull << lane) - 1ull;
    for (int it = 0; it < 4; ++it) {
        int chunk = blockIdx.x * 1024 + it * 256 + threadIdx.x;
        uint4 v = ((const uint4*)(bits + (size_t)b * NPTS))[chunk];
        uint32_t n0 = (uint32_t)chunk * 4;
        uint32_t ks[4] = {v.x, v.y, v.z, v.w};
        #pragma unroll
        for (int i = 0; i < 4; ++i) {
            bool sel = (ks[i] >> 8) >= T;
            uint64_t m = __ballot(sel);
            if (m) {
                int leader = __ffsll((unsigned long long)m) - 1;
                uint32_t base = 0;
                if (lane == leader) base = atomicAdd(&ctrl[b * 16 + 3], (uint32_t)__popcll(m));
                base = __shfl(base, leader, 64);
                if (sel) {
                    uint32_t pos = base + (uint32_t)__popcll(m & lmask);
                    if (pos < CAP)
                        cand[(size_t)b * CAP + pos] = ((uint64_t)(~ks[i]) << 32) | (uint64_t)(n0 + i);
                }
            }
        }
    }
}

// ---------------- partial ranks over key slices ----------------
__global__ __launch_bounds__(256) void k_rank1(
    const uint64_t* __restrict__ cand, const uint32_t* __restrict__ ctrl,
    uint32_t* __restrict__ grank)
{
    __shared__ uint64_t keys[SLICE_LEN];
    int b = blockIdx.z;
    uint32_t C = ctrl[b * 16 + 3];
    if (C > CAP) C = CAP;
    uint32_t k0 = blockIdx.y * SLICE_LEN;
    if (k0 >= C) return;
    uint32_t nk = C - k0; if (nk > SLICE_LEN) nk = SLICE_LEN;
    for (uint32_t i = threadIdx.x; i < nk; i += 256)
        keys[i] = cand[(size_t)b * CAP + k0 + i];
    __syncthreads();
    uint32_t item = blockIdx.x * 256 + threadIdx.x;
    if (item >= C) return;
    uint64_t me = cand[(size_t)b * CAP + item];
    uint32_t r = 0;
    #pragma unroll 16
    for (uint32_t i = 0; i < nk; ++i) r += (keys[i] < me) ? 1u : 0u;
    atomicAdd(&grank[b * CAP + item], r);
}

// ---------------- gather by rank ----------------
__global__ __launch_bounds__(256) void k_rank2(
    const uint64_t* __restrict__ cand, const uint32_t* __restrict__ ctrl,
    const uint32_t* __restrict__ grank,
    const float* __restrict__ box, const float* __restrict__ cls, float* __restrict__ out)
{
    int b = blockIdx.y;
    uint32_t C = ctrl[b * 16 + 3];
    if (C > CAP) C = CAP;
    uint32_t item = blockIdx.x * 256 + threadIdx.x;
    if (item >= C) return;
    uint64_t me = cand[(size_t)b * CAP + item];
    uint32_t rank = grank[b * CAP + item];
    if (rank < KSEL) {
        uint32_t n = (uint32_t)me;
        const float* bp = box + ((size_t)b * NPTS + n) * 7;
        float* ob = out + OBOX + ((size_t)b * KSEL + rank) * 7;
        #pragma unroll
        for (int c = 0; c < 7; ++c) ob[c] = bp[c];
        const float* cp = cls + ((size_t)b * NPTS + n) * 3;
        float* oc = out + OCLS + ((size_t)b * KSEL + rank) * 3;
        #pragma unroll
        for (int c = 0; c < 3; ++c) oc[c] = cp[c];
    }
}

// ---------------- fused conv1+bn+relu+conv2+bn+relu+heads ----------------
// grid (64, NB): 64 output positions per block; 256 threads.
__global__ __launch_bounds__(256) void k_conv(
    const float* __restrict__ c1w, const float* __restrict__ g1v, const float* __restrict__ b1v,
    const float* __restrict__ m1v, const float* __restrict__ v1v,
    const float* __restrict__ c2w, const float* __restrict__ g2v, const float* __restrict__ b2v,
    const float* __restrict__ m2v, const float* __restrict__ v2v,
    const float* __restrict__ binw, const float* __restrict__ binb,
    const float* __restrict__ resw, const float* __restrict__ resb,
    float* __restrict__ out)
{
    __shared__ __align__(16) float w1s[960];       // [(i*3+tap)*32 + c]
    __shared__ __align__(16) float b1s[32];
    __shared__ __align__(16) float w2s[6144];      // [(i*3+tap)*64 + o]
    __shared__ __align__(16) float b2s[64];
    __shared__ __align__(16) float hws[6][64];     // bin0..4, res
    __shared__ __align__(16) float xin[10][80];    // x at global pos tile0-2+k2, k2<68
    __shared__ __align__(16) float x1s[32][68];    // x1 at global pos tile0-1+k, k<66
    __shared__ __align__(16) float x2t[64][68];    // [pos][o]

    int tid = threadIdx.x;
    int b = blockIdx.y;
    int tile0 = blockIdx.x * 64;
    const float* boxsel = out + OBOX + (size_t)b * KSEL * 7;
    const float* clssel = out + OCLS + (size_t)b * KSEL * 3;

    // ---- stage folded weights ----
    for (int t = tid; t < 960; t += 256) {         // c1w layout [c][i][tap]
        int c = t / 30, r = t - c * 30, i = r / 3, tap = r - i * 3;
        float inv = g1v[c] * rsqrtf(v1v[c] + 1e-5f);
        w1s[(i * 3 + tap) * 32 + c] = c1w[t] * inv;
    }
    if (tid < 32) {
        float inv = g1v[tid] * rsqrtf(v1v[tid] + 1e-5f);
        b1s[tid] = b1v[tid] - m1v[tid] * inv;
    }
    for (int t = tid; t < 6144; t += 256) {        // c2w layout [o][i][tap]
        int o = t / 96, r = t - o * 96, i = r / 3, tap = r - i * 3;
        float inv = g2v[o] * rsqrtf(v2v[o] + 1e-5f);
        w2s[(i * 3 + tap) * 64 + o] = c2w[t] * inv;
    }
    if (tid >= 64 && tid < 128) {
        int o = tid - 64;
        float inv = g2v[o] * rsqrtf(v2v[o] + 1e-5f);
        b2s[o] = b2v[o] - m2v[o] * inv;
    }
    for (int t = tid; t < 384; t += 256)
        ((float*)hws)[t] = (t < 320) ? binw[t] : resw[t - 320];

    // ---- stage input tile (halo 2) ----
    for (int u = tid; u < 680; u += 256) {
        int c = u / 68, k2 = u - c * 68;
        int g = tile0 + k2 - 2;
        float val = 0.f;
        if (g >= 0 && g < KSEL) val = (c < 7) ? boxsel[g * 7 + c] : clssel[g * 3 + (c - 7)];
        xin[c][k2] = val;
    }
    __syncthreads();

    // ---- conv1: thread (c, kg): 9 positions ----
    {
        int c = tid & 31, kg = tid >> 5;
        int k0 = kg * 9;
        int nk = 66 - k0; if (nk > 9) nk = 9;      // kg=7 -> 3
        float a[9];
        #pragma unroll
        for (int kk = 0; kk < 9; ++kk) a[kk] = b1s[c];
        #pragma unroll 2
        for (int i = 0; i < 10; ++i) {
            float xv[11];
            #pragma unroll
            for (int j = 0; j < 11; ++j) xv[j] = xin[i][k0 + j];
            #pragma unroll
            for (int tap = 0; tap < 3; ++tap) {
                float w = w1s[(i * 3 + tap) * 32 + c];
                #pragma unroll
                for (int kk = 0; kk < 9; ++kk) a[kk] = fmaf(w, xv[kk + tap], a[kk]);
            }
        }
        for (int kk = 0; kk < nk; ++kk) {
            int k = k0 + kk, gp = tile0 + k - 1;
            x1s[c][k] = (gp >= 0 && gp < KSEL) ? fmaxf(a[kk], 0.f) : 0.f;
        }
    }
    __syncthreads();

    // ---- conv2: thread (o, pg): 16 positions ----
    {
        int o = tid & 63, pg = tid >> 6;
        int p0 = pg * 16;
        float acc[16];
        float bz = b2s[o];
        #pragma unroll
        for (int kk = 0; kk < 16; ++kk) acc[kk] = bz;
        #pragma unroll 4
        for (int i = 0; i < 32; ++i) {
            float4 xq[5];
            const float4* xr = (const float4*)&x1s[i][p0];
            #pragma unroll
            for (int q = 0; q < 5; ++q) xq[q] = xr[q];
            const float* xf = (const float*)xq;
            float w0 = w2s[(i * 3 + 0) * 64 + o];
            float w1 = w2s[(i * 3 + 1) * 64 + o];
            float w2 = w2s[(i * 3 + 2) * 64 + o];
            #pragma unroll
            for (int kk = 0; kk < 16; ++kk) {
                float t0 = fmaf(w0, xf[kk], acc[kk]);
                t0 = fmaf(w1, xf[kk + 1], t0);
                acc[kk] = fmaf(w2, xf[kk + 2], t0);
            }
        }
        #pragma unroll
        for (int kk = 0; kk < 16; ++kk)
            x2t[p0 + kk][o] = fmaxf(acc[kk], 0.f);
    }
    __syncthreads();

    // ---- heads: thread (p, g) ----
    {
        int p = tid & 63, g = tid >> 6;
        const float4* xr = (const float4*)&x2t[p][0];
        const float4* hw4 = (const float4*)hws;
        size_t gpos = (size_t)b * KSEL + (size_t)(tile0 + p);
        if (g < 2) {
            int j0 = g * 2, j1 = j0 + 1;
            float s0 = 0.f, s1 = 0.f;
            #pragma unroll
            for (int q = 0; q < 16; ++q) {
                float4 xv = xr[q];
                float4 wa = hw4[j0 * 16 + q];
                float4 wb = hw4[j1 * 16 + q];
                s0 = fmaf(xv.x, wa.x, s0); s0 = fmaf(xv.y, wa.y, s0);
                s0 = fmaf(xv.z, wa.z, s0); s0 = fmaf(xv.w, wa.w, s0);
                s1 = fmaf(xv.x, wb.x, s1); s1 = fmaf(xv.y, wb.y, s1);
                s1 = fmaf(xv.z, wb.z, s1); s1 = fmaf(xv.w, wb.w, s1);
            }
            out[OBIN + gpos * 5 + j0] = s0 + binb[j0];
            out[OBIN + gpos * 5 + j1] = s1 + binb[j1];
        } else {
            int j = (g == 2) ? 4 : 5;
            float s = 0.f;
            #pragma unroll
            for (int q = 0; q < 16; ++q) {
                float4 xv = xr[q];
                float4 wa = hw4[j * 16 + q];
                s = fmaf(xv.x, wa.x, s); s = fmaf(xv.y, wa.y, s);
                s = fmaf(xv.z, wa.z, s); s = fmaf(xv.w, wa.w, s);
            }
            if (g == 2) out[OBIN + gpos * 5 + 4] = s + binb[4];
            else        out[ORES + gpos]         = s + resb[0];
        }
    }
}

extern "C" void kernel_launch(void* const* d_in, const int* in_sizes, int n_in,
                              void* d_out, int out_size, void* d_ws, size_t ws_size,
                              hipStream_t stream)
{
    const float* box  = (const float*)d_in[0];
    const float* cls  = (const float*)d_in[1];
    const float* c1w  = (const float*)d_in[2];
    const float* g1   = (const float*)d_in[3];
    const float* b1   = (const float*)d_in[4];
    const float* m1   = (const float*)d_in[5];
    const float* v1   = (const float*)d_in[6];
    const float* c2w  = (const float*)d_in[7];
    const float* g2   = (const float*)d_in[8];
    const float* b2   = (const float*)d_in[9];
    const float* m2   = (const float*)d_in[10];
    const float* v2   = (const float*)d_in[11];
    const float* binw = (const float*)d_in[12];
    const float* binb = (const float*)d_in[13];
    const float* resw = (const float*)d_in[14];
    const float* resb = (const float*)d_in[15];
    float* out = (float*)d_out;
    char* ws = (char*)d_ws;
    if (ws_size < WS_NEEDED) return;

    uint32_t* bits  = (uint32_t*)(ws + OFF_BITS);
    uint32_t* h8    = (uint32_t*)(ws + OFF_H8);
    uint32_t* h16   = (uint32_t*)(ws + OFF_H16);
    uint32_t* ctrl  = (uint32_t*)(ws + OFF_CTRL);
    uint32_t* grank = (uint32_t*)(ws + OFF_GRANK);
    uint64_t* cand  = (uint64_t*)(ws + OFF_CAND);

    hipMemsetAsync(ws + OFF_H8, 0, (size_t)MEMSET_LEN, stream);
    k_score_hist<<<dim3(64, NB), 256, 0, stream>>>(cls, bits, h8);
    k_scan8<<<NB, 256, 0, stream>>>(h8, ctrl);
    k_hist16<<<dim3(64, NB), 256, 0, stream>>>(bits, ctrl, h16);
    k_scan16<<<NB, 256, 0, stream>>>(h16, ctrl);
    k_compact<<<dim3(64, NB), 256, 0, stream>>>(bits, ctrl, cand);
    k_rank1<<<dim3(CAP / 256, SLICES, NB), 256, 0, stream>>>(cand, ctrl, grank);
    k_rank2<<<dim3(CAP / 256, NB), 256, 0, stream>>>(cand, ctrl, grank, box, cls, out);
    k_conv<<<dim3(64, NB), 256, 0, stream>>>(c1w, g1, b1, m1, v1, c2w, g2, b2, m2, v2,
                                             binw, binb, resw, resb, out);
}

// Round 6
// 120.829 us; speedup vs baseline: 2.5351x; 1.3577x over previous
//
#include <hip/hip_runtime.h>
#include <stdint.h>

#define NPTS 262144
#define NB 4
#define KSEL 4096
#define CAP 8192
#define SLICES 8
#define SLICE_LEN (CAP / SLICES)   // 1024 keys, 8 KB LDS
#define CBLK 128                   // compact blocks per batch

// ---- workspace layout (bytes) ----
#define OFF_BITS  0ULL
#define OFF_H8    (4ULL*NPTS*NB)                       // 4 MB
#define OFF_H16   (OFF_H8 + 4ULL*256*NB)               // +4 KB
#define OFF_CTRL  (OFF_H16 + 4ULL*65536*NB)            // +1 MB
#define OFF_GRANK (OFF_CTRL + 1024ULL)
#define OFF_CAND  (OFF_GRANK + 4ULL*CAP*NB)            // 128 KB grank
#define WS_NEEDED (OFF_CAND + 8ULL*CAP*NB)             // +256 KB cand
#define MEMSET_LEN (OFF_CAND - OFF_H8)                 // h8+h16+ctrl+grank

// ---- output layout (float elements) ----
#define OBIN 0
#define ORES (NB*KSEL*5)           // 81920
#define OBOX (ORES + NB*KSEL)      // 98304
#define OCLS (OBOX + NB*KSEL*7)    // 212992

// ctrl per batch (16 u32): [0]=P8 [1]=count_above_P8 [2]=T24 [3]=cand_count

__device__ __forceinline__ uint32_t key_of(float mx) {
    uint32_t b = __float_as_uint(mx);
    uint32_t mask = ((int32_t)b >> 31) | 0x80000000u;
    return b ^ mask;
}

// ---------------- keys + hi8 histogram ----------------
__global__ __launch_bounds__(256) void k_score_hist(
    const float* __restrict__ cls, uint32_t* __restrict__ bits, uint32_t* __restrict__ h8)
{
    __shared__ uint32_t lh[8][256];
    for (int i = threadIdx.x; i < 2048; i += 256) ((uint32_t*)lh)[i] = 0;
    __syncthreads();
    int b = blockIdx.y;
    int sub = threadIdx.x >> 5;          // 8 sub-hists (half-wave granularity)
    for (int it = 0; it < 4; ++it) {
        int chunk = blockIdx.x * 1024 + it * 256 + threadIdx.x;    // uint4-chunk in [0,65536)
        const float4* p = (const float4*)(cls + ((size_t)b * NPTS + (size_t)chunk * 4) * 3);
        float4 v0 = p[0], v1 = p[1], v2 = p[2];
        uint4 o;
        o.x = key_of(fmaxf(fmaxf(v0.x, v0.y), v0.z));
        o.y = key_of(fmaxf(fmaxf(v0.w, v1.x), v1.y));
        o.z = key_of(fmaxf(fmaxf(v1.z, v1.w), v2.x));
        o.w = key_of(fmaxf(fmaxf(v2.y, v2.z), v2.w));
        ((uint4*)(bits + (size_t)b * NPTS))[chunk] = o;
        atomicAdd(&lh[sub][o.x >> 24], 1u);
        atomicAdd(&lh[sub][o.y >> 24], 1u);
        atomicAdd(&lh[sub][o.z >> 24], 1u);
        atomicAdd(&lh[sub][o.w >> 24], 1u);
    }
    __syncthreads();
    int i = threadIdx.x;                 // one bin per thread
    uint32_t c = 0;
    #pragma unroll
    for (int s = 0; s < 8; ++s) c += lh[s][i];
    if (c) atomicAdd(&h8[b * 256 + i], c);
}

// ---------------- find P8 ----------------
__global__ __launch_bounds__(256) void k_scan8(
    const uint32_t* __restrict__ h8, uint32_t* __restrict__ ctrl)
{
    __shared__ uint32_t s[256];
    int b = blockIdx.x;
    s[threadIdx.x] = h8[b * 256 + threadIdx.x];
    __syncthreads();
    if (threadIdx.x == 0) {
        uint32_t running = 0;
        for (int i = 255; i >= 0; --i) {
            if (running + s[i] >= (uint32_t)KSEL) {
                ctrl[b * 16 + 0] = (uint32_t)i;      // P8
                ctrl[b * 16 + 1] = running;          // strictly above
                break;
            }
            running += s[i];
        }
    }
}

// ---------------- mid16 histogram of the P8 bucket ----------------
__global__ __launch_bounds__(256) void k_hist16(
    const uint32_t* __restrict__ bits, const uint32_t* __restrict__ ctrl, uint32_t* __restrict__ h16)
{
    int b = blockIdx.y;
    uint32_t P8 = ctrl[b * 16 + 0];
    for (int it = 0; it < 4; ++it) {
        int chunk = blockIdx.x * 1024 + it * 256 + threadIdx.x;
        uint4 v = ((const uint4*)(bits + (size_t)b * NPTS))[chunk];
        if ((v.x >> 24) == P8) atomicAdd(&h16[b * 65536 + ((v.x >> 8) & 0xFFFFu)], 1u);
        if ((v.y >> 24) == P8) atomicAdd(&h16[b * 65536 + ((v.y >> 8) & 0xFFFFu)], 1u);
        if ((v.z >> 24) == P8) atomicAdd(&h16[b * 65536 + ((v.z >> 8) & 0xFFFFu)], 1u);
        if ((v.w >> 24) == P8) atomicAdd(&h16[b * 65536 + ((v.w >> 8) & 0xFFFFu)], 1u);
    }
}

// ---------------- find T24 (coalesced wave-parallel scan of 64K bins) ----------------
__global__ __launch_bounds__(256) void k_scan16(
    const uint32_t* __restrict__ h16, uint32_t* __restrict__ ctrl)
{
    int b = blockIdx.x;
    const uint32_t* h = h16 + (size_t)b * 65536;
    __shared__ uint32_t part[256];
    __shared__ uint32_t binsS[256];
    __shared__ int segS;
    __shared__ uint32_t runS;
    uint32_t K = (uint32_t)KSEL - ctrl[b * 16 + 1];
    int w = threadIdx.x >> 6, lane = threadIdx.x & 63;
    for (int seg = w; seg < 256; seg += 4) {
        uint4 v = ((const uint4*)(h + seg * 256))[lane];
        uint32_t s = v.x + v.y + v.z + v.w;
        #pragma unroll
        for (int off = 32; off; off >>= 1) s += __shfl_xor(s, off, 64);
        if (lane == 0) part[seg] = s;
    }
    __syncthreads();
    if (threadIdx.x == 0) {
        uint32_t running = 0; int seg = 0;
        for (int t = 255; t >= 0; --t) {
            if (running + part[t] >= K) { seg = t; break; }
            running += part[t];
        }
        segS = seg; runS = running;
    }
    __syncthreads();
    binsS[threadIdx.x] = h[segS * 256 + threadIdx.x];
    __syncthreads();
    if (threadIdx.x == 0) {
        uint32_t running = runS;
        for (int i = 255; i >= 0; --i) {
            running += binsS[i];
            if (running >= K) {
                ctrl[b * 16 + 2] = (ctrl[b * 16 + 0] << 16) | (uint32_t)(segS * 256 + i);
                break;
            }
        }
    }
}

// ---------------- compact superset (key>>8 >= T24), block-aggregated atomic ----------------
// grid (CBLK, NB); each block: 512 uint4 chunks = 2048 elements; ONE global atomic.
__global__ __launch_bounds__(256) void k_compact(
    const uint32_t* __restrict__ bits, uint32_t* __restrict__ ctrl, uint64_t* __restrict__ cand)
{
    __shared__ uint32_t wbase[4];
    int b = blockIdx.y;
    uint32_t T = ctrl[b * 16 + 2];
    int lane = threadIdx.x & 63;
    int wave = threadIdx.x >> 6;
    uint64_t lmask = (1ull << lane) - 1ull;

    int chunk0 = blockIdx.x * 512 + threadIdx.x;
    const uint4* src = (const uint4*)(bits + (size_t)b * NPTS);
    uint4 v0 = src[chunk0];
    uint4 v1 = src[chunk0 + 256];
    uint32_t ks[8] = {v0.x, v0.y, v0.z, v0.w, v1.x, v1.y, v1.z, v1.w};
    bool sel[8];
    #pragma unroll
    for (int i = 0; i < 8; ++i) sel[i] = (ks[i] >> 8) >= T;

    // phase 1: per-wave count
    uint32_t wsum = 0;
    #pragma unroll
    for (int i = 0; i < 8; ++i) wsum += (uint32_t)__popcll(__ballot(sel[i]));
    if (lane == 0) wbase[wave] = wsum;
    __syncthreads();
    // phase 2: one atomic per block, wave prefixes
    if (threadIdx.x == 0) {
        uint32_t c0 = wbase[0], c1 = wbase[1], c2 = wbase[2], c3 = wbase[3];
        uint32_t tot = c0 + c1 + c2 + c3;
        uint32_t base = tot ? atomicAdd(&ctrl[b * 16 + 3], tot) : 0u;
        wbase[0] = base;
        wbase[1] = base + c0;
        wbase[2] = base + c0 + c1;
        wbase[3] = base + c0 + c1 + c2;
    }
    __syncthreads();
    // phase 3: scatter
    uint32_t off = wbase[wave];
    #pragma unroll
    for (int i = 0; i < 8; ++i) {
        uint64_t m = __ballot(sel[i]);
        if (sel[i]) {
            uint32_t pos = off + (uint32_t)__popcll(m & lmask);
            uint32_t n = (uint32_t)(chunk0 + (i < 4 ? 0 : 256)) * 4 + (uint32_t)(i & 3);
            if (pos < CAP)
                cand[(size_t)b * CAP + pos] = ((uint64_t)(~ks[i]) << 32) | (uint64_t)n;
        }
        off += (uint32_t)__popcll(m);
    }
}

// ---------------- partial ranks over key slices ----------------
__global__ __launch_bounds__(256) void k_rank1(
    const uint64_t* __restrict__ cand, const uint32_t* __restrict__ ctrl,
    uint32_t* __restrict__ grank)
{
    __shared__ uint64_t keys[SLICE_LEN];
    int b = blockIdx.z;
    uint32_t C = ctrl[b * 16 + 3];
    if (C > CAP) C = CAP;
    uint32_t k0 = blockIdx.y * SLICE_LEN;
    if (k0 >= C) return;
    uint32_t nk = C - k0; if (nk > SLICE_LEN) nk = SLICE_LEN;
    for (uint32_t i = threadIdx.x; i < nk; i += 256)
        keys[i] = cand[(size_t)b * CAP + k0 + i];
    __syncthreads();
    uint32_t item = blockIdx.x * 256 + threadIdx.x;
    if (item >= C) return;
    uint64_t me = cand[(size_t)b * CAP + item];
    uint32_t r = 0;
    #pragma unroll 16
    for (uint32_t i = 0; i < nk; ++i) r += (keys[i] < me) ? 1u : 0u;
    atomicAdd(&grank[b * CAP + item], r);
}

// ---------------- gather by rank ----------------
__global__ __launch_bounds__(256) void k_rank2(
    const uint64_t* __restrict__ cand, const uint32_t* __restrict__ ctrl,
    const uint32_t* __restrict__ grank,
    const float* __restrict__ box, const float* __restrict__ cls, float* __restrict__ out)
{
    int b = blockIdx.y;
    uint32_t C = ctrl[b * 16 + 3];
    if (C > CAP) C = CAP;
    uint32_t item = blockIdx.x * 256 + threadIdx.x;
    if (item >= C) return;
    uint64_t me = cand[(size_t)b * CAP + item];
    uint32_t rank = grank[b * CAP + item];
    if (rank < KSEL) {
        uint32_t n = (uint32_t)me;
        const float* bp = box + ((size_t)b * NPTS + n) * 7;
        float* ob = out + OBOX + ((size_t)b * KSEL + rank) * 7;
        #pragma unroll
        for (int c = 0; c < 7; ++c) ob[c] = bp[c];
        const float* cp = cls + ((size_t)b * NPTS + n) * 3;
        float* oc = out + OCLS + ((size_t)b * KSEL + rank) * 3;
        #pragma unroll
        for (int c = 0; c < 3; ++c) oc[c] = cp[c];
    }
}

// ---------------- fused conv1+bn+relu+conv2+bn+relu+heads ----------------
// grid (64, NB): 64 output positions per block; 256 threads.
__global__ __launch_bounds__(256) void k_conv(
    const float* __restrict__ c1w, const float* __restrict__ g1v, const float* __restrict__ b1v,
    const float* __restrict__ m1v, const float* __restrict__ v1v,
    const float* __restrict__ c2w, const float* __restrict__ g2v, const float* __restrict__ b2v,
    const float* __restrict__ m2v, const float* __restrict__ v2v,
    const float* __restrict__ binw, const float* __restrict__ binb,
    const float* __restrict__ resw, const float* __restrict__ resb,
    float* __restrict__ out)
{
    __shared__ __align__(16) float w1s[960];       // [(i*3+tap)*32 + c]
    __shared__ __align__(16) float b1s[32];
    __shared__ __align__(16) float w2s[6144];      // [(i*3+tap)*64 + o]
    __shared__ __align__(16) float b2s[64];
    __shared__ __align__(16) float hws[6][64];     // bin0..4, res
    __shared__ __align__(16) float xin[10][80];    // x at global pos tile0-2+k2, k2<68
    __shared__ __align__(16) float x1s[32][68];    // x1 at global pos tile0-1+k, k<66
    __shared__ __align__(16) float x2t[64][68];    // [pos][o]

    int tid = threadIdx.x;
    int b = blockIdx.y;
    int tile0 = blockIdx.x * 64;
    const float* boxsel = out + OBOX + (size_t)b * KSEL * 7;
    const float* clssel = out + OCLS + (size_t)b * KSEL * 3;

    // ---- stage folded weights ----
    for (int t = tid; t < 960; t += 256) {         // c1w layout [c][i][tap]
        int c = t / 30, r = t - c * 30, i = r / 3, tap = r - i * 3;
        float inv = g1v[c] * rsqrtf(v1v[c] + 1e-5f);
        w1s[(i * 3 + tap) * 32 + c] = c1w[t] * inv;
    }
    if (tid < 32) {
        float inv = g1v[tid] * rsqrtf(v1v[tid] + 1e-5f);
        b1s[tid] = b1v[tid] - m1v[tid] * inv;
    }
    for (int t = tid; t < 6144; t += 256) {        // c2w layout [o][i][tap]
        int o = t / 96, r = t - o * 96, i = r / 3, tap = r - i * 3;
        float inv = g2v[o] * rsqrtf(v2v[o] + 1e-5f);
        w2s[(i * 3 + tap) * 64 + o] = c2w[t] * inv;
    }
    if (tid >= 64 && tid < 128) {
        int o = tid - 64;
        float inv = g2v[o] * rsqrtf(v2v[o] + 1e-5f);
        b2s[o] = b2v[o] - m2v[o] * inv;
    }
    for (int t = tid; t < 384; t += 256)
        ((float*)hws)[t] = (t < 320) ? binw[t] : resw[t - 320];

    // ---- stage input tile (halo 2) ----
    for (int u = tid; u < 680; u += 256) {
        int c = u / 68, k2 = u - c * 68;
        int g = tile0 + k2 - 2;
        float val = 0.f;
        if (g >= 0 && g < KSEL) val = (c < 7) ? boxsel[g * 7 + c] : clssel[g * 3 + (c - 7)];
        xin[c][k2] = val;
    }
    __syncthreads();

    // ---- conv1: thread (c, kg): 9 positions ----
    {
        int c = tid & 31, kg = tid >> 5;
        int k0 = kg * 9;
        int nk = 66 - k0; if (nk > 9) nk = 9;      // kg=7 -> 3
        float a[9];
        #pragma unroll
        for (int kk = 0; kk < 9; ++kk) a[kk] = b1s[c];
        #pragma unroll 2
        for (int i = 0; i < 10; ++i) {
            float xv[11];
            #pragma unroll
            for (int j = 0; j < 11; ++j) xv[j] = xin[i][k0 + j];
            #pragma unroll
            for (int tap = 0; tap < 3; ++tap) {
                float w = w1s[(i * 3 + tap) * 32 + c];
                #pragma unroll
                for (int kk = 0; kk < 9; ++kk) a[kk] = fmaf(w, xv[kk + tap], a[kk]);
            }
        }
        for (int kk = 0; kk < nk; ++kk) {
            int k = k0 + kk, gp = tile0 + k - 1;
            x1s[c][k] = (gp >= 0 && gp < KSEL) ? fmaxf(a[kk], 0.f) : 0.f;
        }
    }
    __syncthreads();

    // ---- conv2: thread (o, pg): 16 positions ----
    {
        int o = tid & 63, pg = tid >> 6;
        int p0 = pg * 16;
        float acc[16];
        float bz = b2s[o];
        #pragma unroll
        for (int kk = 0; kk < 16; ++kk) acc[kk] = bz;
        #pragma unroll 4
        for (int i = 0; i < 32; ++i) {
            float4 xq[5];
            const float4* xr = (const float4*)&x1s[i][p0];
            #pragma unroll
            for (int q = 0; q < 5; ++q) xq[q] = xr[q];
            const float* xf = (const float*)xq;
            float w0 = w2s[(i * 3 + 0) * 64 + o];
            float w1 = w2s[(i * 3 + 1) * 64 + o];
            float w2 = w2s[(i * 3 + 2) * 64 + o];
            #pragma unroll
            for (int kk = 0; kk < 16; ++kk) {
                float t0 = fmaf(w0, xf[kk], acc[kk]);
                t0 = fmaf(w1, xf[kk + 1], t0);
                acc[kk] = fmaf(w2, xf[kk + 2], t0);
            }
        }
        #pragma unroll
        for (int kk = 0; kk < 16; ++kk)
            x2t[p0 + kk][o] = fmaxf(acc[kk], 0.f);
    }
    __syncthreads();

    // ---- heads: thread (p, g) ----
    {
        int p = tid & 63, g = tid >> 6;
        const float4* xr = (const float4*)&x2t[p][0];
        const float4* hw4 = (const float4*)hws;
        size_t gpos = (size_t)b * KSEL + (size_t)(tile0 + p);
        if (g < 2) {
            int j0 = g * 2, j1 = j0 + 1;
            float s0 = 0.f, s1 = 0.f;
            #pragma unroll
            for (int q = 0; q < 16; ++q) {
                float4 xv = xr[q];
                float4 wa = hw4[j0 * 16 + q];
                float4 wb = hw4[j1 * 16 + q];
                s0 = fmaf(xv.x, wa.x, s0); s0 = fmaf(xv.y, wa.y, s0);
                s0 = fmaf(xv.z, wa.z, s0); s0 = fmaf(xv.w, wa.w, s0);
                s1 = fmaf(xv.x, wb.x, s1); s1 = fmaf(xv.y, wb.y, s1);
                s1 = fmaf(xv.z, wb.z, s1); s1 = fmaf(xv.w, wb.w, s1);
            }
            out[OBIN + gpos * 5 + j0] = s0 + binb[j0];
            out[OBIN + gpos * 5 + j1] = s1 + binb[j1];
        } else {
            int j = (g == 2) ? 4 : 5;
            float s = 0.f;
            #pragma unroll
            for (int q = 0; q < 16; ++q) {
                float4 xv = xr[q];
                float4 wa = hw4[j * 16 + q];
                s = fmaf(xv.x, wa.x, s); s = fmaf(xv.y, wa.y, s);
                s = fmaf(xv.z, wa.z, s); s = fmaf(xv.w, wa.w, s);
            }
            if (g == 2) out[OBIN + gpos * 5 + 4] = s + binb[4];
            else        out[ORES + gpos]         = s + resb[0];
        }
    }
}

extern "C" void kernel_launch(void* const* d_in, const int* in_sizes, int n_in,
                              void* d_out, int out_size, void* d_ws, size_t ws_size,
                              hipStream_t stream)
{
    const float* box  = (const float*)d_in[0];
    const float* cls  = (const float*)d_in[1];
    const float* c1w  = (const float*)d_in[2];
    const float* g1   = (const float*)d_in[3];
    const float* b1   = (const float*)d_in[4];
    const float* m1   = (const float*)d_in[5];
    const float* v1   = (const float*)d_in[6];
    const float* c2w  = (const float*)d_in[7];
    const float* g2   = (const float*)d_in[8];
    const float* b2   = (const float*)d_in[9];
    const float* m2   = (const float*)d_in[10];
    const float* v2   = (const float*)d_in[11];
    const float* binw = (const float*)d_in[12];
    const float* binb = (const float*)d_in[13];
    const float* resw = (const float*)d_in[14];
    const float* resb = (const float*)d_in[15];
    float* out = (float*)d_out;
    char* ws = (char*)d_ws;
    if (ws_size < WS_NEEDED) return;

    uint32_t* bits  = (uint32_t*)(ws + OFF_BITS);
    uint32_t* h8    = (uint32_t*)(ws + OFF_H8);
    uint32_t* h16   = (uint32_t*)(ws + OFF_H16);
    uint32_t* ctrl  = (uint32_t*)(ws + OFF_CTRL);
    uint32_t* grank = (uint32_t*)(ws + OFF_GRANK);
    uint64_t* cand  = (uint64_t*)(ws + OFF_CAND);

    hipMemsetAsync(ws + OFF_H8, 0, (size_t)MEMSET_LEN, stream);
    k_score_hist<<<dim3(64, NB), 256, 0, stream>>>(cls, bits, h8);
    k_scan8<<<NB, 256, 0, stream>>>(h8, ctrl);
    k_hist16<<<dim3(64, NB), 256, 0, stream>>>(bits, ctrl, h16);
    k_scan16<<<NB, 256, 0, stream>>>(h16, ctrl);
    k_compact<<<dim3(CBLK, NB), 256, 0, stream>>>(bits, ctrl, cand);
    k_rank1<<<dim3(CAP / 256, SLICES, NB), 256, 0, stream>>>(cand, ctrl, grank);
    k_rank2<<<dim3(CAP / 256, NB), 256, 0, stream>>>(cand, ctrl, grank, box, cls, out);
    k_conv<<<dim3(64, NB), 256, 0, stream>>>(c1w, g1, b1, m1, v1, c2w, g2, b2, m2, v2,
                                             binw, binb, resw, resb, out);
}

// Round 7
// 102.564 us; speedup vs baseline: 2.9866x; 1.1781x over previous
//
#include <hip/hip_runtime.h>
#include <stdint.h>

#define NPTS 262144
#define NB 4
#define KSEL 4096
#define CAP 8192
#define SLICES 8
#define SLICE_LEN (CAP / SLICES)   // 1024 keys, 8 KB LDS
#define CBLK 128                   // compact blocks per batch

// ---- workspace layout (bytes) ----
#define OFF_BITS  0ULL
#define OFF_H8    (4ULL*NPTS*NB)                       // 4 MB
#define OFF_H12   (OFF_H8 + 4ULL*256*NB)               // +4 KB
#define OFF_CTRL  (OFF_H12 + 4ULL*4096*NB)             // +64 KB
#define OFF_GRANK (OFF_CTRL + 1024ULL)
#define OFF_CAND  (OFF_GRANK + 4ULL*CAP*NB)            // 128 KB grank
#define WS_NEEDED (OFF_CAND + 8ULL*CAP*NB)             // +256 KB cand
#define MEMSET_LEN (OFF_CAND - OFF_H8)                 // h8+h12+ctrl+grank (~197 KB)

// ---- output layout (float elements) ----
#define OBIN 0
#define ORES (NB*KSEL*5)           // 81920
#define OBOX (ORES + NB*KSEL)      // 98304
#define OCLS (OBOX + NB*KSEL*7)    // 212992

// ctrl per batch (16 u32): [0]=P8 [1]=count_above_P8 [2]=T20 [3]=cand_count

__device__ __forceinline__ uint32_t key_of(float mx) {
    uint32_t b = __float_as_uint(mx);
    uint32_t mask = ((int32_t)b >> 31) | 0x80000000u;
    return b ^ mask;
}

// ---------------- keys + hi8 histogram ----------------
__global__ __launch_bounds__(256) void k_score_hist(
    const float* __restrict__ cls, uint32_t* __restrict__ bits, uint32_t* __restrict__ h8)
{
    __shared__ uint32_t lh[8][256];
    for (int i = threadIdx.x; i < 2048; i += 256) ((uint32_t*)lh)[i] = 0;
    __syncthreads();
    int b = blockIdx.y;
    int sub = threadIdx.x >> 5;          // 8 sub-hists (half-wave granularity)
    for (int it = 0; it < 4; ++it) {
        int chunk = blockIdx.x * 1024 + it * 256 + threadIdx.x;    // uint4-chunk in [0,65536)
        const float4* p = (const float4*)(cls + ((size_t)b * NPTS + (size_t)chunk * 4) * 3);
        float4 v0 = p[0], v1 = p[1], v2 = p[2];
        uint4 o;
        o.x = key_of(fmaxf(fmaxf(v0.x, v0.y), v0.z));
        o.y = key_of(fmaxf(fmaxf(v0.w, v1.x), v1.y));
        o.z = key_of(fmaxf(fmaxf(v1.z, v1.w), v2.x));
        o.w = key_of(fmaxf(fmaxf(v2.y, v2.z), v2.w));
        ((uint4*)(bits + (size_t)b * NPTS))[chunk] = o;
        atomicAdd(&lh[sub][o.x >> 24], 1u);
        atomicAdd(&lh[sub][o.y >> 24], 1u);
        atomicAdd(&lh[sub][o.z >> 24], 1u);
        atomicAdd(&lh[sub][o.w >> 24], 1u);
    }
    __syncthreads();
    int i = threadIdx.x;                 // one bin per thread
    uint32_t c = 0;
    #pragma unroll
    for (int s = 0; s < 8; ++s) c += lh[s][i];
    if (c) atomicAdd(&h8[b * 256 + i], c);
}

// ---------------- find P8 ----------------
__global__ __launch_bounds__(256) void k_scan8(
    const uint32_t* __restrict__ h8, uint32_t* __restrict__ ctrl)
{
    __shared__ uint32_t s[256];
    int b = blockIdx.x;
    s[threadIdx.x] = h8[b * 256 + threadIdx.x];
    __syncthreads();
    if (threadIdx.x == 0) {
        uint32_t running = 0;
        for (int i = 255; i >= 0; --i) {
            if (running + s[i] >= (uint32_t)KSEL) {
                ctrl[b * 16 + 0] = (uint32_t)i;      // P8
                ctrl[b * 16 + 1] = running;          // strictly above
                break;
            }
            running += s[i];
        }
    }
}

// ---------------- 12-bit histogram of the P8 bucket ----------------
__global__ __launch_bounds__(256) void k_hist12(
    const uint32_t* __restrict__ bits, const uint32_t* __restrict__ ctrl, uint32_t* __restrict__ h12)
{
    int b = blockIdx.y;
    uint32_t P8 = ctrl[b * 16 + 0];
    for (int it = 0; it < 4; ++it) {
        int chunk = blockIdx.x * 1024 + it * 256 + threadIdx.x;
        uint4 v = ((const uint4*)(bits + (size_t)b * NPTS))[chunk];
        if ((v.x >> 24) == P8) atomicAdd(&h12[b * 4096 + ((v.x >> 12) & 0xFFFu)], 1u);
        if ((v.y >> 24) == P8) atomicAdd(&h12[b * 4096 + ((v.y >> 12) & 0xFFFu)], 1u);
        if ((v.z >> 24) == P8) atomicAdd(&h12[b * 4096 + ((v.z >> 12) & 0xFFFu)], 1u);
        if ((v.w >> 24) == P8) atomicAdd(&h12[b * 4096 + ((v.w >> 12) & 0xFFFu)], 1u);
    }
}

// ---------------- find T20: bulk-load 4096 bins to LDS, scan ----------------
__global__ __launch_bounds__(256) void k_scan12(
    const uint32_t* __restrict__ h12, uint32_t* __restrict__ ctrl)
{
    __shared__ uint32_t bins[4096];
    __shared__ uint32_t part[256];
    int b = blockIdx.x;
    const uint4* src = (const uint4*)(h12 + (size_t)b * 4096);
    for (int i = threadIdx.x; i < 1024; i += 256)
        ((uint4*)bins)[i] = src[i];
    __syncthreads();
    uint32_t s = 0;
    int base = threadIdx.x * 16;
    #pragma unroll
    for (int j = 0; j < 16; ++j) s += bins[base + j];
    part[threadIdx.x] = s;
    __syncthreads();
    if (threadIdx.x == 0) {
        uint32_t K = (uint32_t)KSEL - ctrl[b * 16 + 1];
        uint32_t running = 0; int seg = 0;
        for (int t = 255; t >= 0; --t) {
            if (running + part[t] >= K) { seg = t; break; }
            running += part[t];
        }
        for (int i = 15; i >= 0; --i) {
            running += bins[seg * 16 + i];
            if (running >= K) {
                ctrl[b * 16 + 2] = (ctrl[b * 16 + 0] << 12) | (uint32_t)(seg * 16 + i);
                break;
            }
        }
    }
}

// ---------------- compact superset (key>>12 >= T20), block-aggregated atomic ----------------
// grid (CBLK, NB); each block: 512 uint4 chunks = 2048 elements; ONE global atomic.
__global__ __launch_bounds__(256) void k_compact(
    const uint32_t* __restrict__ bits, uint32_t* __restrict__ ctrl, uint64_t* __restrict__ cand)
{
    __shared__ uint32_t wbase[4];
    int b = blockIdx.y;
    uint32_t T = ctrl[b * 16 + 2];
    int lane = threadIdx.x & 63;
    int wave = threadIdx.x >> 6;
    uint64_t lmask = (1ull << lane) - 1ull;

    int chunk0 = blockIdx.x * 512 + threadIdx.x;
    const uint4* src = (const uint4*)(bits + (size_t)b * NPTS);
    uint4 v0 = src[chunk0];
    uint4 v1 = src[chunk0 + 256];
    uint32_t ks[8] = {v0.x, v0.y, v0.z, v0.w, v1.x, v1.y, v1.z, v1.w};
    bool sel[8];
    #pragma unroll
    for (int i = 0; i < 8; ++i) sel[i] = (ks[i] >> 12) >= T;

    // phase 1: per-wave count
    uint32_t wsum = 0;
    #pragma unroll
    for (int i = 0; i < 8; ++i) wsum += (uint32_t)__popcll(__ballot(sel[i]));
    if (lane == 0) wbase[wave] = wsum;
    __syncthreads();
    // phase 2: one atomic per block, wave prefixes
    if (threadIdx.x == 0) {
        uint32_t c0 = wbase[0], c1 = wbase[1], c2 = wbase[2], c3 = wbase[3];
        uint32_t tot = c0 + c1 + c2 + c3;
        uint32_t base = tot ? atomicAdd(&ctrl[b * 16 + 3], tot) : 0u;
        wbase[0] = base;
        wbase[1] = base + c0;
        wbase[2] = base + c0 + c1;
        wbase[3] = base + c0 + c1 + c2;
    }
    __syncthreads();
    // phase 3: scatter
    uint32_t off = wbase[wave];
    #pragma unroll
    for (int i = 0; i < 8; ++i) {
        uint64_t m = __ballot(sel[i]);
        if (sel[i]) {
            uint32_t pos = off + (uint32_t)__popcll(m & lmask);
            uint32_t n = (uint32_t)(chunk0 + (i < 4 ? 0 : 256)) * 4 + (uint32_t)(i & 3);
            if (pos < CAP)
                cand[(size_t)b * CAP + pos] = ((uint64_t)(~ks[i]) << 32) | (uint64_t)n;
        }
        off += (uint32_t)__popcll(m);
    }
}

// ---------------- partial ranks over key slices ----------------
__global__ __launch_bounds__(256) void k_rank1(
    const uint64_t* __restrict__ cand, const uint32_t* __restrict__ ctrl,
    uint32_t* __restrict__ grank)
{
    __shared__ uint64_t keys[SLICE_LEN];
    int b = blockIdx.z;
    uint32_t C = ctrl[b * 16 + 3];
    if (C > CAP) C = CAP;
    uint32_t k0 = blockIdx.y * SLICE_LEN;
    if (k0 >= C) return;
    uint32_t nk = C - k0; if (nk > SLICE_LEN) nk = SLICE_LEN;
    for (uint32_t i = threadIdx.x; i < nk; i += 256)
        keys[i] = cand[(size_t)b * CAP + k0 + i];
    __syncthreads();
    uint32_t item = blockIdx.x * 256 + threadIdx.x;
    if (item >= C) return;
    uint64_t me = cand[(size_t)b * CAP + item];
    uint32_t r = 0;
    #pragma unroll 16
    for (uint32_t i = 0; i < nk; ++i) r += (keys[i] < me) ? 1u : 0u;
    atomicAdd(&grank[b * CAP + item], r);
}

// ---------------- gather by rank ----------------
__global__ __launch_bounds__(256) void k_rank2(
    const uint64_t* __restrict__ cand, const uint32_t* __restrict__ ctrl,
    const uint32_t* __restrict__ grank,
    const float* __restrict__ box, const float* __restrict__ cls, float* __restrict__ out)
{
    int b = blockIdx.y;
    uint32_t C = ctrl[b * 16 + 3];
    if (C > CAP) C = CAP;
    uint32_t item = blockIdx.x * 256 + threadIdx.x;
    if (item >= C) return;
    uint64_t me = cand[(size_t)b * CAP + item];
    uint32_t rank = grank[b * CAP + item];
    if (rank < KSEL) {
        uint32_t n = (uint32_t)me;
        const float* bp = box + ((size_t)b * NPTS + n) * 7;
        float* ob = out + OBOX + ((size_t)b * KSEL + rank) * 7;
        #pragma unroll
        for (int c = 0; c < 7; ++c) ob[c] = bp[c];
        const float* cp = cls + ((size_t)b * NPTS + n) * 3;
        float* oc = out + OCLS + ((size_t)b * KSEL + rank) * 3;
        #pragma unroll
        for (int c = 0; c < 3; ++c) oc[c] = cp[c];
    }
}

// ---------------- fused conv1+bn+relu+conv2+bn+relu+heads ----------------
// grid (64, NB): 64 output positions per block; 256 threads.
__global__ __launch_bounds__(256) void k_conv(
    const float* __restrict__ c1w, const float* __restrict__ g1v, const float* __restrict__ b1v,
    const float* __restrict__ m1v, const float* __restrict__ v1v,
    const float* __restrict__ c2w, const float* __restrict__ g2v, const float* __restrict__ b2v,
    const float* __restrict__ m2v, const float* __restrict__ v2v,
    const float* __restrict__ binw, const float* __restrict__ binb,
    const float* __restrict__ resw, const float* __restrict__ resb,
    float* __restrict__ out)
{
    __shared__ __align__(16) float w1s[960];       // [(i*3+tap)*32 + c]
    __shared__ __align__(16) float b1s[32];
    __shared__ __align__(16) float w2s[6144];      // [(i*3+tap)*64 + o]
    __shared__ __align__(16) float b2s[64];
    __shared__ __align__(16) float hws[6][64];     // bin0..4, res
    __shared__ __align__(16) float xin[10][80];    // x at global pos tile0-2+k2, k2<68
    __shared__ __align__(16) float x1s[32][68];    // x1 at global pos tile0-1+k, k<66
    __shared__ __align__(16) float x2t[64][68];    // [pos][o]

    int tid = threadIdx.x;
    int b = blockIdx.y;
    int tile0 = blockIdx.x * 64;
    const float* boxsel = out + OBOX + (size_t)b * KSEL * 7;
    const float* clssel = out + OCLS + (size_t)b * KSEL * 3;

    // ---- stage folded weights ----
    for (int t = tid; t < 960; t += 256) {         // c1w layout [c][i][tap]
        int c = t / 30, r = t - c * 30, i = r / 3, tap = r - i * 3;
        float inv = g1v[c] * rsqrtf(v1v[c] + 1e-5f);
        w1s[(i * 3 + tap) * 32 + c] = c1w[t] * inv;
    }
    if (tid < 32) {
        float inv = g1v[tid] * rsqrtf(v1v[tid] + 1e-5f);
        b1s[tid] = b1v[tid] - m1v[tid] * inv;
    }
    for (int t = tid; t < 6144; t += 256) {        // c2w layout [o][i][tap]
        int o = t / 96, r = t - o * 96, i = r / 3, tap = r - i * 3;
        float inv = g2v[o] * rsqrtf(v2v[o] + 1e-5f);
        w2s[(i * 3 + tap) * 64 + o] = c2w[t] * inv;
    }
    if (tid >= 64 && tid < 128) {
        int o = tid - 64;
        float inv = g2v[o] * rsqrtf(v2v[o] + 1e-5f);
        b2s[o] = b2v[o] - m2v[o] * inv;
    }
    for (int t = tid; t < 384; t += 256)
        ((float*)hws)[t] = (t < 320) ? binw[t] : resw[t - 320];

    // ---- stage input tile (halo 2) ----
    for (int u = tid; u < 680; u += 256) {
        int c = u / 68, k2 = u - c * 68;
        int g = tile0 + k2 - 2;
        float val = 0.f;
        if (g >= 0 && g < KSEL) val = (c < 7) ? boxsel[g * 7 + c] : clssel[g * 3 + (c - 7)];
        xin[c][k2] = val;
    }
    __syncthreads();

    // ---- conv1: thread (c, kg): 9 positions ----
    {
        int c = tid & 31, kg = tid >> 5;
        int k0 = kg * 9;
        int nk = 66 - k0; if (nk > 9) nk = 9;      // kg=7 -> 3
        float a[9];
        #pragma unroll
        for (int kk = 0; kk < 9; ++kk) a[kk] = b1s[c];
        #pragma unroll 2
        for (int i = 0; i < 10; ++i) {
            float xv[11];
            #pragma unroll
            for (int j = 0; j < 11; ++j) xv[j] = xin[i][k0 + j];
            #pragma unroll
            for (int tap = 0; tap < 3; ++tap) {
                float w = w1s[(i * 3 + tap) * 32 + c];
                #pragma unroll
                for (int kk = 0; kk < 9; ++kk) a[kk] = fmaf(w, xv[kk + tap], a[kk]);
            }
        }
        for (int kk = 0; kk < nk; ++kk) {
            int k = k0 + kk, gp = tile0 + k - 1;
            x1s[c][k] = (gp >= 0 && gp < KSEL) ? fmaxf(a[kk], 0.f) : 0.f;
        }
    }
    __syncthreads();

    // ---- conv2: thread (o, pg): 16 positions ----
    {
        int o = tid & 63, pg = tid >> 6;
        int p0 = pg * 16;
        float acc[16];
        float bz = b2s[o];
        #pragma unroll
        for (int kk = 0; kk < 16; ++kk) acc[kk] = bz;
        #pragma unroll 4
        for (int i = 0; i < 32; ++i) {
            float4 xq[5];
            const float4* xr = (const float4*)&x1s[i][p0];
            #pragma unroll
            for (int q = 0; q < 5; ++q) xq[q] = xr[q];
            const float* xf = (const float*)xq;
            float w0 = w2s[(i * 3 + 0) * 64 + o];
            float w1 = w2s[(i * 3 + 1) * 64 + o];
            float w2 = w2s[(i * 3 + 2) * 64 + o];
            #pragma unroll
            for (int kk = 0; kk < 16; ++kk) {
                float t0 = fmaf(w0, xf[kk], acc[kk]);
                t0 = fmaf(w1, xf[kk + 1], t0);
                acc[kk] = fmaf(w2, xf[kk + 2], t0);
            }
        }
        #pragma unroll
        for (int kk = 0; kk < 16; ++kk)
            x2t[p0 + kk][o] = fmaxf(acc[kk], 0.f);
    }
    __syncthreads();

    // ---- heads: thread (p, g) ----
    {
        int p = tid & 63, g = tid >> 6;
        const float4* xr = (const float4*)&x2t[p][0];
        const float4* hw4 = (const float4*)hws;
        size_t gpos = (size_t)b * KSEL + (size_t)(tile0 + p);
        if (g < 2) {
            int j0 = g * 2, j1 = j0 + 1;
            float s0 = 0.f, s1 = 0.f;
            #pragma unroll
            for (int q = 0; q < 16; ++q) {
                float4 xv = xr[q];
                float4 wa = hw4[j0 * 16 + q];
                float4 wb = hw4[j1 * 16 + q];
                s0 = fmaf(xv.x, wa.x, s0); s0 = fmaf(xv.y, wa.y, s0);
                s0 = fmaf(xv.z, wa.z, s0); s0 = fmaf(xv.w, wa.w, s0);
                s1 = fmaf(xv.x, wb.x, s1); s1 = fmaf(xv.y, wb.y, s1);
                s1 = fmaf(xv.z, wb.z, s1); s1 = fmaf(xv.w, wb.w, s1);
            }
            out[OBIN + gpos * 5 + j0] = s0 + binb[j0];
            out[OBIN + gpos * 5 + j1] = s1 + binb[j1];
        } else {
            int j = (g == 2) ? 4 : 5;
            float s = 0.f;
            #pragma unroll
            for (int q = 0; q < 16; ++q) {
                float4 xv = xr[q];
                float4 wa = hw4[j * 16 + q];
                s = fmaf(xv.x, wa.x, s); s = fmaf(xv.y, wa.y, s);
                s = fmaf(xv.z, wa.z, s); s = fmaf(xv.w, wa.w, s);
            }
            if (g == 2) out[OBIN + gpos * 5 + 4] = s + binb[4];
            else        out[ORES + gpos]         = s + resb[0];
        }
    }
}

extern "C" void kernel_launch(void* const* d_in, const int* in_sizes, int n_in,
                              void* d_out, int out_size, void* d_ws, size_t ws_size,
                              hipStream_t stream)
{
    const float* box  = (const float*)d_in[0];
    const float* cls  = (const float*)d_in[1];
    const float* c1w  = (const float*)d_in[2];
    const float* g1   = (const float*)d_in[3];
    const float* b1   = (const float*)d_in[4];
    const float* m1   = (const float*)d_in[5];
    const float* v1   = (const float*)d_in[6];
    const float* c2w  = (const float*)d_in[7];
    const float* g2   = (const float*)d_in[8];
    const float* b2   = (const float*)d_in[9];
    const float* m2   = (const float*)d_in[10];
    const float* v2   = (const float*)d_in[11];
    const float* binw = (const float*)d_in[12];
    const float* binb = (const float*)d_in[13];
    const float* resw = (const float*)d_in[14];
    const float* resb = (const float*)d_in[15];
    float* out = (float*)d_out;
    char* ws = (char*)d_ws;
    if (ws_size < WS_NEEDED) return;

    uint32_t* bits  = (uint32_t*)(ws + OFF_BITS);
    uint32_t* h8    = (uint32_t*)(ws + OFF_H8);
    uint32_t* h12   = (uint32_t*)(ws + OFF_H12);
    uint32_t* ctrl  = (uint32_t*)(ws + OFF_CTRL);
    uint32_t* grank = (uint32_t*)(ws + OFF_GRANK);
    uint64_t* cand  = (uint64_t*)(ws + OFF_CAND);

    hipMemsetAsync(ws + OFF_H8, 0, (size_t)MEMSET_LEN, stream);
    k_score_hist<<<dim3(64, NB), 256, 0, stream>>>(cls, bits, h8);
    k_scan8<<<NB, 256, 0, stream>>>(h8, ctrl);
    k_hist12<<<dim3(64, NB), 256, 0, stream>>>(bits, ctrl, h12);
    k_scan12<<<NB, 256, 0, stream>>>(h12, ctrl);
    k_compact<<<dim3(CBLK, NB), 256, 0, stream>>>(bits, ctrl, cand);
    k_rank1<<<dim3(CAP / 256, SLICES, NB), 256, 0, stream>>>(cand, ctrl, grank);
    k_rank2<<<dim3(CAP / 256, NB), 256, 0, stream>>>(cand, ctrl, grank, box, cls, out);
    k_conv<<<dim3(64, NB), 256, 0, stream>>>(c1w, g1, b1, m1, v1, c2w, g2, b2, m2, v2,
                                             binw, binb, resw, resb, out);
}